// Round 9
// baseline (172.041 us; speedup 1.0000x reference)
//
#include <hip/hip_runtime.h>
#include <hip/hip_bf16.h>

// Problem constants
#define N_TOK 8192
#define INL   512
#define OUTL  512
#define NE    8
#define NI    16
#define EOFF  (OUTL * INL)   // elems per expert in wt

typedef unsigned short ushort_t;
typedef unsigned int   uint_t;
typedef short  short8  __attribute__((ext_vector_type(8)));
typedef float  floatx4 __attribute__((ext_vector_type(4)));

// ---------------- workspace layout (bytes), ends 4376640 ----
#define WS_BET    2112u      // float[4096]   : bet_eff[e][d] = bet + gam*b
#define WS_SELE   18496u     // int[8192]     : e0 | e1<<8
#define WS_SELW   51264u     // float4[8192]  : {rw0*gam0, rw1*gam1, rw0, rw1}
#define WS_WT     182336u    // ushort[8*512*512] : W^T bf16 [e][d][l]

__device__ __forceinline__ ushort_t f2bf(float f) {
    uint_t b = __float_as_uint(f);
    return (ushort_t)((b + 0x7FFFu + ((b >> 16) & 1u)) >> 16);   // RNE
}
__device__ __forceinline__ uint_t pkbf(float a, float b) {
    __hip_bfloat162 h = __float22bfloat162_rn(make_float2(a, b));  // v_cvt_pk_bf16_f32
    union { __hip_bfloat162 h2; uint_t u; } cv;
    cv.h2 = h;
    return cv.u;
}
// async global->LDS DMA, 16 B per lane; LDS dest = wave-uniform base + lane*16
__device__ __forceinline__ void dma16(const ushort_t* g, ushort_t* l) {
    __builtin_amdgcn_global_load_lds(
        (const __attribute__((address_space(1))) void*)g,
        (__attribute__((address_space(3))) void*)l,
        16, 0, 0);
}

// ================= K1: fused prep =================
// blocks [0,512):   Wt transpose/convert  (e = bx>>6; tile = bx&63)
// blocks [512,640): bet_eff               (e = b>>4; dBase = (b&15)*32)
// blocks [640,1152):router + inlined stats (16 tokens/block)
__global__ __launch_bounds__(256)
void k_prep(const float* __restrict__ x,
            const float* __restrict__ ins,
            const float* __restrict__ gate_w,
            const float* __restrict__ expert_w,
            const float* __restrict__ expert_b,
            const float* __restrict__ gamma_w,
            const float* __restrict__ beta_w,
            const float* __restrict__ rmod_w,
            ushort_t* __restrict__ wt,
            float* __restrict__ wsBet,
            int* __restrict__ selE, float4* __restrict__ selW) {
    __shared__ __align__(16) char smem[19072];
    int bx = blockIdx.x;
    int tid = threadIdx.x;

    if (bx < 512) {
        // ---- Wt: [e][l][d] fp32 -> [e][d][l] bf16 ----
        float (*tile)[65] = (float(*)[65])smem;
        int e = bx >> 6, rem = bx & 63;
        int lt = (rem >> 3) * 64, dt = (rem & 7) * 64;
        int dIdx = tid & 63, lq = tid >> 6;
        for (int i = 0; i < 16; ++i) {
            int l = lq * 16 + i;
            tile[l][dIdx] = expert_w[(e * INL + lt + l) * OUTL + dt + dIdx];
        }
        __syncthreads();
        int lIdx = tid & 63, dq = tid >> 6;
        for (int i = 0; i < 16; ++i) {
            int d = dq * 16 + i;
            wt[(e * OUTL + dt + d) * INL + lt + lIdx] = f2bf(tile[lIdx][d]);
        }
        return;
    }

    if (bx < 640) {
        // ---- bet_eff[e][d] = (1/NI) sum_h s[h] beta[e,h,d] + gam_e * b[e,d] ----
        float* sS  = (float*)smem;          // [512]
        float* red = sS + 512;              // [256]
        float* gamS = red + 256;            // [1]
        int b2 = bx - 512;
        int e = b2 >> 4, dBase = (b2 & 15) * 32;
        for (int h = tid; h < INL; h += 256) {
            float a = 0.f;
            for (int n = 0; n < NI; ++n) a += ins[n * INL + h];
            sS[h] = a;
        }
        __syncthreads();
        if (tid < 64) {
            float g = 0.f;
            for (int j = 0; j < 8; ++j) g += sS[tid * 8 + j] * gamma_w[e * INL + tid * 8 + j];
            for (int off = 32; off >= 1; off >>= 1) g += __shfl_xor(g, off, 64);
            if (tid == 0) gamS[0] = g * (1.f / NI);
        }
        int doff = tid & 31, hq = tid >> 5;
        float a = 0.f;
        for (int j = 0; j < 64; ++j) {
            int h = hq * 64 + j;
            a += sS[h] * beta_w[(e * INL + h) * OUTL + dBase + doff];
        }
        red[tid] = a;
        __syncthreads();
        if (tid < 32) {
            float t = 0.f;
            for (int k = 0; k < 8; ++k) t += red[k * 32 + tid];
            int d = dBase + tid;
            wsBet[e * OUTL + d] = t * (1.f / NI) + gamS[0] * expert_b[e * OUTL + d];
        }
        return;
    }

    // ---- router with inlined stats ----
    float* gateT = (float*)smem;            // [8*512]
    float* sS    = gateT + NE * INL;        // [512]
    float* pg    = sS + 512;                // [64]
    float* pr    = pg + 64;                 // [64]
    float* gg    = pr + 64;                 // [8] gam
    float* rg    = gg + 8;                  // [8] rgam
    int rb = bx - 640;

    for (int i = 0; i < 16; ++i) {
        int f = tid + 256 * i;
        float v = gate_w[f];
        gateT[(f & 7) * INL + (f >> 3)] = v;
    }
    for (int h = tid; h < INL; h += 256) {
        float a = 0.f;
        for (int n = 0; n < NI; ++n) a += ins[n * INL + h];
        sS[h] = a;
    }
    __syncthreads();
    if (tid < 64) {
        int e = tid & 7, qq = tid >> 3;
        float g = 0.f, r = 0.f;
        for (int j = 0; j < 64; ++j) {
            int h = qq * 64 + j;
            float sv = sS[h];
            g += sv * gamma_w[e * INL + h];
            r += sv * rmod_w[h * NE + e];
        }
        pg[tid] = g; pr[tid] = r;
    }
    __syncthreads();
    if (tid < NE) {
        float g = 0.f, r = 0.f;
        for (int qq = 0; qq < 8; ++qq) { g += pg[qq * 8 + tid]; r += pr[qq * 8 + tid]; }
        gg[tid] = g * (1.f / NI);
        rg[tid] = r * (1.f / NI);
    }
    __syncthreads();

    int w = tid >> 6, lane = tid & 63;
    int tbase = rb * 16 + w * 4;
    for (int tt = 0; tt < 4; ++tt) {
        int t = tbase + tt;
        float2 xv[4];
        for (int i = 0; i < 4; ++i)
            xv[i] = *(const float2*)(x + (size_t)t * INL + 2 * lane + 128 * i);

        float acc[NE];
        for (int e = 0; e < NE; ++e) acc[e] = 0.f;
        for (int i = 0; i < 4; ++i) {
            int c = 2 * lane + 128 * i;
            for (int e = 0; e < NE; ++e)
                acc[e] += xv[i].x * gateT[e * INL + c] + xv[i].y * gateT[e * INL + c + 1];
        }
        for (int e = 0; e < NE; ++e) {
            float a = acc[e];
            for (int off = 32; off >= 1; off >>= 1) a += __shfl_xor(a, off, 64);
            acc[e] = a;
        }
        float logit[NE];
        for (int e = 0; e < NE; ++e) logit[e] = acc[e] + rg[e];

        int i0 = 0; float m0 = logit[0];
        for (int e = 1; e < NE; ++e) if (logit[e] > m0) { m0 = logit[e]; i0 = e; }
        int i1 = -1; float m1 = -3.4e38f;
        for (int e = 0; e < NE; ++e) if (e != i0 && logit[e] > m1) { m1 = logit[e]; i1 = e; }

        float S = 0.f;
        for (int e = 0; e < NE; ++e) S += expf(logit[e] - m0);
        float rw0 = 1.0f / S;
        float rw1 = expf(m1 - m0) / S;

        if (lane == 0) {
            selE[t] = i0 | (i1 << 8);
            selW[t] = make_float4(rw0 * gg[i0], rw1 * gg[i1], rw0, rw1);
        }
    }
}

// ================= K2: dense all-expert GEMM =================
// Block = M128 x N64, 4 waves. 16 barrier-steps: step = (kc, expert-half).
// Per step: 4 expert B-subtiles (32 KB) staged via global_load_lds (dbuf),
// 64 MFMA per wave (~310 cyc) + VALU A-pack co-issued -> covers DMA drain.
// A: per-lane fp32 regs, loaded once per kc, scaled per expert, packed bf16.
// LDS rotate swizzle per subtile: (col,k) at col*64 + ((k/8 + col)&7)*8.
__global__ __launch_bounds__(256, 2)
void k_gemm(const float* __restrict__ x, const ushort_t* __restrict__ wt,
            const int* __restrict__ selE, const float4* __restrict__ selW,
            const float* __restrict__ wsBet, float* __restrict__ out) {
    int bx = blockIdx.x;
    int rt = bx & 63;                  // token slab: rows rt*128..+128
    int ct = bx >> 6;                  // col slab: ct*64..+64
    __shared__ ushort_t Blds[2 * 4 * 4096];   // 64 KB: [buf][expert][col][kslot]

    int tid = threadIdx.x;
    int wid = tid >> 6, lane = tid & 63;
    int wm = wid * 32;
    int mrow = lane & 15, laneq = lane >> 4, q8 = laneq * 8, qr = laneq * 4;

    // per-lane combine weights for this lane's 2 A rows
    float wv[2][NE];
    for (int mt = 0; mt < 2; ++mt) {
        int tok = rt * 128 + wm + mt * 16 + mrow;
        int es = selE[tok];
        float4 w4 = selW[tok];
        int e0 = es & 255, e1 = es >> 8;
        for (int e = 0; e < NE; ++e)
            wv[mt][e] = (e == e0) ? w4.x : ((e == e1) ? w4.y : 0.f);
    }

    // A row pointers (8 contiguous fp32 at k-offset q8)
    const float* arow[2];
    for (int mt = 0; mt < 2; ++mt)
        arow[mt] = x + (size_t)(rt * 128 + wm + mt * 16 + mrow) * INL + q8;

    // B staging: thread stages chunks c0=tid, c1=tid+256 per expert subtile.
    // chunk c -> col=c>>3, kslot=c&7, src kgrp=(kslot-col)&7  (rotate swizzle)
    int c0 = tid, c1 = tid + 256;
    int col0 = c0 >> 3, kg0 = ((c0 & 7) - col0) & 7;
    int col1 = c1 >> 3, kg1 = ((c1 & 7) - col1) & 7;
    const ushort_t* pB0 = wt + (size_t)(ct * 64 + col0) * INL + kg0 * 8;
    const ushort_t* pB1 = wt + (size_t)(ct * 64 + col1) * INL + kg1 * 8;
    ushort_t* ldsW0 = &Blds[0] + (wid * 64) * 8;         // + buf*16384 + ei*4096
    ushort_t* ldsW1 = &Blds[0] + (256 + wid * 64) * 8;

    // fragment read swizzle
    int fcol[4], frot0[4];
    for (int nt = 0; nt < 4; ++nt) {
        fcol[nt] = nt * 16 + mrow;
        frot0[nt] = (laneq + fcol[nt]) & 7;
    }

    floatx4 comb[2][4];
    for (int mt = 0; mt < 2; ++mt)
        for (int nt = 0; nt < 4; ++nt)
            comb[mt][nt] = (floatx4){0.f, 0.f, 0.f, 0.f};

    // prologue: DMA step 0 (kc=0, experts 0..3) into buf 0
    for (int ei = 0; ei < 4; ++ei) {
        size_t off = (size_t)ei * EOFF;
        dma16(pB0 + off, ldsW0 + ei * 4096);
        dma16(pB1 + off, ldsW1 + ei * 4096);
    }
    // A fragments for kc=0
    float4 ar[2][2][2];
    for (int mt = 0; mt < 2; ++mt)
        for (int ks = 0; ks < 2; ++ks) {
            ar[mt][ks][0] = *(const float4*)(arow[mt]);
            ar[mt][ks][1] = *(const float4*)(arow[mt] + 4);
        }
    // fix: proper kc=0 offsets (ks*32)
    for (int mt = 0; mt < 2; ++mt)
        for (int ks = 0; ks < 2; ++ks) {
            const float* p = arow[mt] + ks * 32;
            ar[mt][ks][0] = *(const float4*)p;
            ar[mt][ks][1] = *(const float4*)(p + 4);
        }

    #pragma unroll 1
    for (int step = 0; step < 16; ++step) {
        int buf = step & 1;
        int kc = step >> 1, eh = step & 1;
        __syncthreads();   // drains this step's DMA; prev compute on other buf done

        // issue DMA for next step into other buffer (flies under compute)
        if (step < 15) {
            int ns = step + 1;
            int nkc = ns >> 1, neh = ns & 1, nb = ns & 1;
            for (int ei = 0; ei < 4; ++ei) {
                size_t off = (size_t)(neh * 4 + ei) * EOFF + (size_t)nkc * 64;
                dma16(pB0 + off, ldsW0 + nb * 16384 + ei * 4096);
                dma16(pB1 + off, ldsW1 + nb * 16384 + ei * 4096);
            }
        }
        // A loads for next kc issued during the eh==1 step (consumed next step)
        float4 arn[2][2][2];
        bool haveArn = (eh == 1 && kc < 7);
        if (haveArn) {
            for (int mt = 0; mt < 2; ++mt)
                for (int ks = 0; ks < 2; ++ks) {
                    const float* p = arow[mt] + (kc + 1) * 64 + ks * 32;
                    arn[mt][ks][0] = *(const float4*)p;
                    arn[mt][ks][1] = *(const float4*)(p + 4);
                }
        }

        // compute: 4 expert subtiles from this buffer
        #pragma unroll
        for (int ei = 0; ei < 4; ++ei) {
            int e = eh * 4 + ei;
            const ushort_t* B = &Blds[buf * 16384 + ei * 4096];
            short8 bf[4][2];
            for (int nt = 0; nt < 4; ++nt) {
                int cb = fcol[nt] * 64;
                bf[nt][0] = *(const short8*)&B[cb + frot0[nt] * 8];
                bf[nt][1] = *(const short8*)&B[cb + ((frot0[nt] + 4) & 7) * 8];
            }
            for (int mt = 0; mt < 2; ++mt) {
                float w = wv[mt][e];
                for (int ks = 0; ks < 2; ++ks) {
                    union { uint4 u; short8 s; } af;
                    float4 a0 = ar[mt][ks][0], a1 = ar[mt][ks][1];
                    af.u.x = pkbf(a0.x * w, a0.y * w);
                    af.u.y = pkbf(a0.z * w, a0.w * w);
                    af.u.z = pkbf(a1.x * w, a1.y * w);
                    af.u.w = pkbf(a1.z * w, a1.w * w);
                    for (int nt = 0; nt < 4; ++nt)
                        comb[mt][nt] = __builtin_amdgcn_mfma_f32_16x16x32_bf16(
                            af.s, bf[nt][ks], comb[mt][nt], 0, 0, 0);
                }
            }
        }
        // roll A registers at end of the eh==1 step
        if (haveArn) {
            for (int mt = 0; mt < 2; ++mt)
                for (int ks = 0; ks < 2; ++ks)
                    for (int h = 0; h < 2; ++h) ar[mt][ks][h] = arn[mt][ks][h];
        }
    }

    // epilogue: out = comb + rw0*bet_eff[e0] + rw1*bet_eff[e1], single store
    for (int mt = 0; mt < 2; ++mt) {
        for (int ri = 0; ri < 4; ++ri) {
            int row = wm + mt * 16 + qr + ri;
            int tok = rt * 128 + row;
            int es = selE[tok];
            float4 w4 = selW[tok];
            int e0 = es & 255, e1 = es >> 8;
            for (int nt = 0; nt < 4; ++nt) {
                int col = ct * 64 + nt * 16 + mrow;
                float bet = w4.z * wsBet[e0 * OUTL + col] + w4.w * wsBet[e1 * OUTL + col];
                out[(size_t)tok * OUTL + col] = comb[mt][nt][ri] + bet;
            }
        }
    }
}

extern "C" void kernel_launch(void* const* d_in, const int* in_sizes, int n_in,
                              void* d_out, int out_size, void* d_ws, size_t ws_size,
                              hipStream_t stream) {
    const float* x        = (const float*)d_in[0];
    const float* ins      = (const float*)d_in[1];
    const float* gate_w   = (const float*)d_in[2];
    const float* expert_w = (const float*)d_in[3];
    const float* expert_b = (const float*)d_in[4];
    const float* gamma_w  = (const float*)d_in[5];
    const float* beta_w   = (const float*)d_in[6];
    const float* rmod_w   = (const float*)d_in[7];
    float* out = (float*)d_out;

    char* ws = (char*)d_ws;
    float*    wsBet  = (float*)(ws + WS_BET);
    int*      selE   = (int*)(ws + WS_SELE);
    float4*   selW   = (float4*)(ws + WS_SELW);
    ushort_t* wt     = (ushort_t*)(ws + WS_WT);

    k_prep<<<1152, 256, 0, stream>>>(x, ins, gate_w, expert_w, expert_b,
                                     gamma_w, beta_w, rmod_w,
                                     wt, wsBet, selE, selW);
    k_gemm<<<512, 256, 0, stream>>>(x, wt, selE, selW, wsBet, out);
}